// Round 2
// baseline (372.601 us; speedup 1.0000x reference)
//
#include <hip/hip_runtime.h>

typedef __attribute__((ext_vector_type(8))) short bf16x8;
typedef __attribute__((ext_vector_type(4))) short short4v;
typedef __attribute__((ext_vector_type(4))) float f32x4;
typedef __attribute__((ext_vector_type(16))) float f32x16;
typedef __attribute__((ext_vector_type(2))) unsigned int u32x2;

#define DEV static __device__ __forceinline__

// scale folded into Q projection: 1/sqrt(DK) * log2(e)
#define QSC 0.1804165017087941f

DEV unsigned short f2b(float f) {
  union { float f; unsigned int i; } v; v.f = f;
  unsigned int x = v.i;
  return (unsigned short)((x + 0x7FFFu + ((x >> 16) & 1u)) >> 16);  // RNE
}

// async 16B global->LDS (dest must equal wave-uniform base + lane*16)
DEV void cp16(const unsigned short* g, unsigned short* l) {
  __builtin_amdgcn_global_load_lds(
      (const __attribute__((address_space(1))) void*)g,
      (__attribute__((address_space(3))) void*)l, 16, 0, 0);
}

// packed f32x2 -> bf16x2 (RNE), lo in low 16 bits
DEV unsigned int cvtpk(float lo, float hi) {
  unsigned int r;
  asm("v_cvt_pk_bf16_f32 %0, %1, %2" : "=v"(r) : "v"(lo), "v"(hi));
  return r;
}

// ---------------------------------------------------------------------------
// fp32 -> bf16 converts
// ---------------------------------------------------------------------------
__global__ void cvt_kernel(const float* __restrict__ in,
                           unsigned short* __restrict__ out, int n, float scale) {
  const int i = (blockIdx.x * blockDim.x + threadIdx.x) * 4;
  if (i < n) {
    const float4 v = *(const float4*)&in[i];
    short4v o;
    o[0] = (short)f2b(v.x * scale); o[1] = (short)f2b(v.y * scale);
    o[2] = (short)f2b(v.z * scale); o[3] = (short)f2b(v.w * scale);
    *(short4v*)&out[i] = o;
  }
}

// All 7 converts in one launch. Blocks [0,24576): x_Q/x_K/x_V (8192 each);
// [24576,28672): Wq/Wk/Wv/Wo (1024 each). Wq is pre-scaled by QSC.
__global__ void cvt_all(const float* __restrict__ xq, const float* __restrict__ xk,
                        const float* __restrict__ xv, const float* __restrict__ wq,
                        const float* __restrict__ wk, const float* __restrict__ wv,
                        const float* __restrict__ wo, unsigned short* __restrict__ X,
                        unsigned short* __restrict__ W) {
  const int b = blockIdx.x;
  const float* p;
  unsigned short* out;
  float scale = 1.f;
  int i;
  if (b < 24576) {
    const int seg = b >> 13, ib = b & 8191;
    p = (seg == 0) ? xq : (seg == 1) ? xk : xv;
    out = X + (size_t)seg * 8388608;
    i = (ib * 256 + threadIdx.x) * 4;
  } else {
    const int bb = b - 24576;
    const int seg = bb >> 10, ib = bb & 1023;
    p = (seg == 0) ? wq : (seg == 1) ? wk : (seg == 2) ? wv : wo;
    out = W + (size_t)seg * 1048576;
    if (seg == 0) scale = QSC;
    i = (ib * 256 + threadIdx.x) * 4;
  }
  const float4 v = *(const float4*)&p[i];
  short4v o;
  o[0] = (short)f2b(v.x * scale); o[1] = (short)f2b(v.y * scale);
  o[2] = (short)f2b(v.z * scale); o[3] = (short)f2b(v.w * scale);
  *(short4v*)&out[i] = o;
}

// ---------------------------------------------------------------------------
// NT GEMM body: Out = A[M,K] * W[N,K]^T + bias*bsc, bf16 in, fp32 accum.
// MODE 0: fp32 Out[m*N+n];  MODE 1: bf16 heads [bh][s][dk];  MODE 2: bf16 [bh][dk][s]
// 128x128 tile, BK=64, 4 waves, 4x4 MFMA/wave. LDS XOR-swizzled at 16B chunks.
// ---------------------------------------------------------------------------
template <int MODE>
DEV void gemm_tile_body(const unsigned short* __restrict__ A,
                        const unsigned short* __restrict__ W,
                        const float* __restrict__ bias, void* __restrict__ OutV,
                        unsigned short* sA, unsigned short* sB,
                        int M, int N, int K, float bsc) {
  const int tid = threadIdx.x;
  const int lane = tid & 63, wave = tid >> 6;
  const int lr = lane & 15, quad = lane >> 4;
  const int bm = blockIdx.x * 128, bn = blockIdx.y * 128;
  const int wm = (wave >> 1) * 64, wn = (wave & 1) * 64;
  const int srow = tid >> 3;                       // 0..31
  const int sdst = (tid & 7) * 8;                  // LDS chunk (forced layout)
  const int ssrc = ((tid & 7) ^ (srow & 7)) * 8;   // swizzled source chunk

  f32x4 acc[4][4] = {};

  for (int kt = 0; kt < K; kt += 64) {
#pragma unroll
    for (int is = 0; is < 4; ++is) {
      const int r = is * 32 + srow;
      cp16(&A[(size_t)(bm + r) * K + kt + ssrc], &sA[r * 64 + sdst]);
      cp16(&W[(size_t)(bn + r) * K + kt + ssrc], &sB[r * 64 + sdst]);
    }
    __syncthreads();
#pragma unroll
    for (int ks = 0; ks < 2; ++ks) {
      bf16x8 af[4], bf[4];
      const int co = (((ks * 4 + quad) ^ (lr & 7)) << 3);
#pragma unroll
      for (int i = 0; i < 4; ++i)
        af[i] = *(const bf16x8*)&sA[(wm + i * 16 + lr) * 64 + co];
#pragma unroll
      for (int j = 0; j < 4; ++j)
        bf[j] = *(const bf16x8*)&sB[(wn + j * 16 + lr) * 64 + co];
#pragma unroll
      for (int i = 0; i < 4; ++i)
#pragma unroll
        for (int j = 0; j < 4; ++j)
          acc[i][j] = __builtin_amdgcn_mfma_f32_16x16x32_bf16(af[i], bf[j], acc[i][j], 0, 0, 0);
    }
    __syncthreads();
  }

  // epilogue: C/D layout col = lane&15, row = quad*4 + reg
#pragma unroll
  for (int j = 0; j < 4; ++j) {
    const int n = bn + wn + j * 16 + lr;
    const float bv = bias[n] * bsc;
#pragma unroll
    for (int i = 0; i < 4; ++i) {
      const int mb = bm + wm + i * 16 + quad * 4;
#pragma unroll
      for (int r = 0; r < 4; ++r) {
        const int m = mb + r;
        const float o = acc[i][j][r] + bv;
        if (MODE == 0) {
          ((float*)OutV)[(size_t)m * N + n] = o;
        } else if (MODE == 1) {
          ((unsigned short*)OutV)[((size_t)((m >> 11) * 16 + (n >> 6)) * 2048 + (m & 2047)) * 64 + (n & 63)] = f2b(o);
        } else {
          ((unsigned short*)OutV)[((size_t)((m >> 11) * 16 + (n >> 6)) * 64 + (n & 63)) * 2048 + (m & 2047)] = f2b(o);
        }
      }
    }
  }
}

template <int MODE>
__global__ __launch_bounds__(256, 3) void gemm_bt(
    const unsigned short* __restrict__ A, const unsigned short* __restrict__ W,
    const float* __restrict__ bias, void* __restrict__ OutV,
    int M, int N, int K, float bsc) {
  __shared__ __align__(16) unsigned short sA[128 * 64];
  __shared__ __align__(16) unsigned short sB[128 * 64];
  gemm_tile_body<MODE>(A, W, bias, OutV, sA, sB, M, N, K, bsc);
}

// Batched Q/K/V projection: z=0 -> Q (MODE1, bias*QSC), z=1 -> K (MODE1), z=2 -> V (MODE2).
__global__ __launch_bounds__(256, 3) void gemm_qkv3(
    const unsigned short* __restrict__ Aall, const unsigned short* __restrict__ Wall,
    const float* __restrict__ b0, const float* __restrict__ b1,
    const float* __restrict__ b2, unsigned short* __restrict__ Out) {
  __shared__ __align__(16) unsigned short sA[128 * 64];
  __shared__ __align__(16) unsigned short sB[128 * 64];
  const int z = blockIdx.z;
  const unsigned short* A = Aall + (size_t)z * 8388608;
  const unsigned short* W = Wall + (size_t)z * 1048576;
  const float* bias = (z == 0) ? b0 : (z == 1) ? b1 : b2;
  const float bsc = (z == 0) ? QSC : 1.f;
  void* OutV = (void*)(Out + (size_t)z * 8388608);
  if (z == 2)
    gemm_tile_body<2>(A, W, bias, OutV, sA, sB, 8192, 1024, 1024, bsc);
  else
    gemm_tile_body<1>(A, W, bias, OutV, sA, sB, 8192, 1024, 1024, bsc);
}

// ---------------------------------------------------------------------------
// Flash attention. Q is pre-scaled by 1/8*log2(e) at projection, so
// P = exp2(S) directly (no per-element fma; constant 2^-M cancels in the
// softmax ratio; exp2 args ~N(0,1.44) -> no overflow).
// Tile split into two kv-halves [QKa->packa->PVa][QKb->packb->PVb] so only
// one 16-reg S accumulator is live at a time and MFMA/VALU interleave.
// 4 blocks/CU (launch_bounds(256,4); 32 KiB LDS, ~124 regs) -> whole grid
// resident. XCD-aware remap: each XCD owns 8 whole bh's -> K/V L2-resident.
// ---------------------------------------------------------------------------
#define ATTN_PACK(SREG, KS0)                                                   \
  {                                                                            \
    float pr[16];                                                              \
    _Pragma("unroll") for (int r = 0; r < 16; ++r) {                           \
      pr[r] = __builtin_amdgcn_exp2f(SREG[r]);                                 \
      rsp[r & 3] += pr[r];                                                     \
    }                                                                          \
    _Pragma("unroll") for (int ksl = 0; ksl < 2; ++ksl) {                      \
      const int o = ksl * 8;                                                   \
      const u32x2 w02 = __builtin_amdgcn_permlane32_swap(                      \
          cvtpk(pr[o + 0], pr[o + 1]), cvtpk(pr[o + 4], pr[o + 5]), false, false); \
      const u32x2 w13 = __builtin_amdgcn_permlane32_swap(                      \
          cvtpk(pr[o + 2], pr[o + 3]), cvtpk(pr[o + 6], pr[o + 7]), false, false); \
      pa[(KS0) + ksl].w[0] = w02[0]; pa[(KS0) + ksl].w[1] = w13[0];            \
      pa[(KS0) + ksl].w[2] = w02[1]; pa[(KS0) + ksl].w[3] = w13[1];            \
    }                                                                          \
  }

#define ATTN_TILE(T, SKB, SVB, DKB, DVB)                                       \
  {                                                                            \
    if ((T) + 1 < 32) {                                                        \
      const int kvn = ((T) + 1) * 64;                                          \
      _Pragma("unroll") for (int is = 0; is < 2; ++is) {                       \
        const int r = is * 32 + sr_;                                           \
        const int sw = (sc_ ^ ((r ^ (r >> 3)) & 7)) * 8;                       \
        cp16(&Kp[(size_t)(kvn + r) * 64 + sw], &DKB[r * 64 + sc_ * 8]);        \
        cp16(&Vp[(size_t)r * 2048 + kvn + sw], &DVB[r * 64 + sc_ * 8]);        \
      }                                                                        \
    }                                                                          \
    {                                                                          \
      f32x16 s0 = {};                                                          \
      __builtin_amdgcn_s_setprio(1);                                           \
      _Pragma("unroll") for (int ks = 0; ks < 4; ++ks) {                       \
        const bf16x8 k0 = *(const bf16x8*)&SKB[rowa + (((ks * 2 + b5) ^ swa) << 3)]; \
        s0 = __builtin_amdgcn_mfma_f32_32x32x16_bf16(k0, qf[ks], s0, 0, 0, 0); \
      }                                                                        \
      __builtin_amdgcn_s_setprio(0);                                           \
      ATTN_PACK(s0, 0)                                                         \
    }                                                                          \
    __builtin_amdgcn_s_setprio(1);                                             \
    _Pragma("unroll") for (int ks = 0; ks < 2; ++ks) {                         \
      const bf16x8 va = *(const bf16x8*)&SVB[rowa + (((ks * 2 + b5) ^ swa) << 3)]; \
      const bf16x8 vb = *(const bf16x8*)&SVB[rowb + (((ks * 2 + b5) ^ swb) << 3)]; \
      oacc0 = __builtin_amdgcn_mfma_f32_32x32x16_bf16(pa[ks].v, va, oacc0, 0, 0, 0); \
      oacc1 = __builtin_amdgcn_mfma_f32_32x32x16_bf16(pa[ks].v, vb, oacc1, 0, 0, 0); \
    }                                                                          \
    __builtin_amdgcn_s_setprio(0);                                             \
    {                                                                          \
      f32x16 s1 = {};                                                          \
      __builtin_amdgcn_s_setprio(1);                                           \
      _Pragma("unroll") for (int ks = 0; ks < 4; ++ks) {                       \
        const bf16x8 k1 = *(const bf16x8*)&SKB[rowb + (((ks * 2 + b5) ^ swb) << 3)]; \
        s1 = __builtin_amdgcn_mfma_f32_32x32x16_bf16(k1, qf[ks], s1, 0, 0, 0); \
      }                                                                        \
      __builtin_amdgcn_s_setprio(0);                                           \
      ATTN_PACK(s1, 2)                                                         \
    }                                                                          \
    __builtin_amdgcn_s_setprio(1);                                             \
    _Pragma("unroll") for (int ks = 2; ks < 4; ++ks) {                         \
      const bf16x8 va = *(const bf16x8*)&SVB[rowa + (((ks * 2 + b5) ^ swa) << 3)]; \
      const bf16x8 vb = *(const bf16x8*)&SVB[rowb + (((ks * 2 + b5) ^ swb) << 3)]; \
      oacc0 = __builtin_amdgcn_mfma_f32_32x32x16_bf16(pa[ks].v, va, oacc0, 0, 0, 0); \
      oacc1 = __builtin_amdgcn_mfma_f32_32x32x16_bf16(pa[ks].v, vb, oacc1, 0, 0, 0); \
    }                                                                          \
    __builtin_amdgcn_s_setprio(0);                                             \
    __syncthreads();                                                           \
  }

__global__ __launch_bounds__(256, 4) void attn_kernel(
    const unsigned short* __restrict__ Qb, const unsigned short* __restrict__ Kb,
    const unsigned short* __restrict__ Vt, unsigned short* __restrict__ Ob) {
  __shared__ __align__(16) unsigned short sK[2][64 * 64];   // [buf][kv][dk]
  __shared__ __align__(16) unsigned short sV[2][64 * 64];   // [buf][dk][kv]

  const int tid = threadIdx.x;
  const int lane = tid & 63;
  const int wave = tid >> 6;
  const int c31 = lane & 31;
  const int b5 = lane >> 5;

  // XCD-aware remap: linear wg -> XCD = wg&7 (round-robin). Give XCD x the
  // 8 bh's [8x, 8x+8) so each bh's K/V (512 KB) stays in one XCD's L2.
  const int wg = blockIdx.y * 16 + blockIdx.x;
  const int j = wg >> 3;
  const int bh = (wg & 7) * 8 + (j >> 4);
  const int q0 = (j & 15) * 128 + wave * 32;

  const size_t base = (size_t)bh * (2048 * 64);
  const unsigned short* __restrict__ Qp = Qb + base;
  const unsigned short* __restrict__ Kp = Kb + base;
  const unsigned short* __restrict__ Vp = Vt + base;

  // Q fragments (pre-scaled): B-operand, lane holds Q[q=c31][dk = ks*16 + b5*8 + j]
  bf16x8 qf[4];
#pragma unroll
  for (int ks = 0; ks < 4; ++ks)
    qf[ks] = *(const bf16x8*)&Qp[(size_t)(q0 + c31) * 64 + ks * 16 + b5 * 8];

  f32x16 oacc0 = {}, oacc1 = {};   // O[q=crow(r,b5)][dk = {c31, 32+c31}]
  float rsp[4] = {0.f, 0.f, 0.f, 0.f};  // 4 independent denom chains
  union PA { unsigned int w[4]; bf16x8 v; };
  PA pa[4];

  const int sr_ = tid >> 3;        // stage row-in-32
  const int sc_ = tid & 7;         // stage dest chunk (forced linear layout)

  const int swa = (c31 ^ (c31 >> 3)) & 7;  // swizzle for row = c31
  const int swb = swa ^ 4;                 // swizzle for row = 32 + c31
  const int rowa = c31 * 64, rowb = (32 + c31) * 64;

  unsigned short* sK0 = &sK[0][0];
  unsigned short* sK1 = &sK[1][0];
  unsigned short* sV0 = &sV[0][0];
  unsigned short* sV1 = &sV[1][0];

  // prologue: stage tile 0
#pragma unroll
  for (int is = 0; is < 2; ++is) {
    const int r = is * 32 + sr_;
    const int sw = (sc_ ^ ((r ^ (r >> 3)) & 7)) * 8;
    cp16(&Kp[(size_t)r * 64 + sw], &sK0[r * 64 + sc_ * 8]);
    cp16(&Vp[(size_t)r * 2048 + sw], &sV0[r * 64 + sc_ * 8]);
  }
  __syncthreads();

  for (int t = 0; t < 32; t += 2) {
    ATTN_TILE(t, sK0, sV0, sK1, sV1);
    ATTN_TILE(t + 1, sK1, sV1, sK0, sV0);
  }

  // finish denominator (q = c31 split across b5 halves), scale, store
  float rs = (rsp[0] + rsp[1]) + (rsp[2] + rsp[3]);
  rs += __shfl_xor(rs, 32);
  const float linv = 1.f / rs;
  const int b = bh >> 4, h = bh & 15;
#pragma unroll
  for (int r = 0; r < 16; ++r) {
    const int crow = (r & 3) + 8 * (r >> 2) + 4 * b5;  // q-local of oacc row r
    const float li = __shfl(linv, crow);               // linv lives at lane q
    unsigned short* op = &Ob[(size_t)(b * 2048 + q0 + crow) * 1024 + h * 64];
    op[c31] = f2b(oacc0[r] * li);
    op[32 + c31] = f2b(oacc1[r] * li);
  }
}

extern "C" void kernel_launch(void* const* d_in, const int* in_sizes, int n_in,
                              void* d_out, int out_size, void* d_ws, size_t ws_size,
                              hipStream_t stream) {
  const float* xq = (const float*)d_in[0];
  const float* xk = (const float*)d_in[1];
  const float* xv = (const float*)d_in[2];
  const float* Wq = (const float*)d_in[3];
  const float* bq = (const float*)d_in[4];
  const float* Wk = (const float*)d_in[5];
  const float* bk = (const float*)d_in[6];
  const float* Wv = (const float*)d_in[7];
  const float* bv = (const float*)d_in[8];
  const float* Wo = (const float*)d_in[9];
  const float* bo = (const float*)d_in[10];

  unsigned short* ws = (unsigned short*)d_ws;
  const size_t SZ = (size_t)8192 * 1024;   // 8M bf16 elems
  const size_t WSZ = (size_t)1024 * 1024;  // 1M bf16 elems

  if (ws_size >= (6 * SZ + 4 * WSZ) * sizeof(unsigned short)) {
    // big-workspace path: 4 launches total
    unsigned short* Xall = ws;                 // 3 x 8M (xq,xk,xv); [0:8M) reused as attn out
    unsigned short* Wall = ws + 3 * SZ;        // 4 x 1M (Wq*QSC, Wk, Wv, Wo)
    unsigned short* Qb = Wall + 4 * WSZ;       // [bh][s][dk]
    unsigned short* Kb = Qb + SZ;              // [bh][s][dk]
    unsigned short* Vt = Kb + SZ;              // [bh][dk][s]

    hipLaunchKernelGGL(cvt_all, dim3(28672), dim3(256), 0, stream,
                       xq, xk, xv, Wq, Wk, Wv, Wo, Xall, Wall);
    hipLaunchKernelGGL(gemm_qkv3, dim3(64, 8, 3), dim3(256), 0, stream,
                       Xall, Wall, bq, bk, bv, Qb);
    hipLaunchKernelGGL(attn_kernel, dim3(16, 64), dim3(256), 0, stream, Qb, Kb, Vt, Xall);
    hipLaunchKernelGGL((gemm_bt<0>), dim3(64, 8), dim3(256), 0, stream,
                       Xall, Wall + 3 * WSZ, bo, d_out, 8192, 1024, 1024, 1.f);
  } else {
    // fallback: sequential buffer-reuse path
    unsigned short* X  = ws;                 // reused: cvt(x_*), then attn output
    unsigned short* Wb = ws + SZ;            // 1M, reused per weight
    unsigned short* Qb = ws + SZ + SZ / 8;   // [bh][s][dk]
    unsigned short* Kb = Qb + SZ;            // [bh][s][dk]
    unsigned short* Vt = Kb + SZ;            // [bh][dk][s]

    const int NX = 8192 * 1024, NW = 1024 * 1024;
    dim3 cbx(256), cgx(NX / 1024), cgw(NW / 1024);
    dim3 gg(64, 8), bb(256);

    hipLaunchKernelGGL(cvt_kernel, cgx, cbx, 0, stream, xq, X, NX, 1.f);
    hipLaunchKernelGGL(cvt_kernel, cgw, cbx, 0, stream, Wq, Wb, NW, QSC);
    hipLaunchKernelGGL((gemm_bt<1>), gg, bb, 0, stream, X, Wb, bq, (void*)Qb, 8192, 1024, 1024, QSC);

    hipLaunchKernelGGL(cvt_kernel, cgx, cbx, 0, stream, xk, X, NX, 1.f);
    hipLaunchKernelGGL(cvt_kernel, cgw, cbx, 0, stream, Wk, Wb, NW, 1.f);
    hipLaunchKernelGGL((gemm_bt<1>), gg, bb, 0, stream, X, Wb, bk, (void*)Kb, 8192, 1024, 1024, 1.f);

    hipLaunchKernelGGL(cvt_kernel, cgx, cbx, 0, stream, xv, X, NX, 1.f);
    hipLaunchKernelGGL(cvt_kernel, cgw, cbx, 0, stream, Wv, Wb, NW, 1.f);
    hipLaunchKernelGGL((gemm_bt<2>), gg, bb, 0, stream, X, Wb, bv, (void*)Vt, 8192, 1024, 1024, 1.f);

    hipLaunchKernelGGL(attn_kernel, dim3(16, 64), bb, 0, stream, Qb, Kb, Vt, X);

    hipLaunchKernelGGL(cvt_kernel, cgw, cbx, 0, stream, Wo, Wb, NW, 1.f);
    hipLaunchKernelGGL((gemm_bt<0>), gg, bb, 0, stream, X, Wb, bo, d_out, 8192, 1024, 1024, 1.f);
  }
}

// Round 3
// 322.349 us; speedup vs baseline: 1.1559x; 1.1559x over previous
//
#include <hip/hip_runtime.h>

typedef __attribute__((ext_vector_type(8))) short bf16x8;
typedef __attribute__((ext_vector_type(4))) short short4v;
typedef __attribute__((ext_vector_type(4))) float f32x4;
typedef __attribute__((ext_vector_type(16))) float f32x16;
typedef __attribute__((ext_vector_type(2))) unsigned int u32x2;

#define DEV static __device__ __forceinline__

// scale folded into Q projection: 1/sqrt(DK) * log2(e)
#define QSC 0.1804165017087941f

DEV unsigned short f2b(float f) {
  union { float f; unsigned int i; } v; v.f = f;
  unsigned int x = v.i;
  return (unsigned short)((x + 0x7FFFu + ((x >> 16) & 1u)) >> 16);  // RNE
}

// async 16B global->LDS (dest must equal wave-uniform base + lane*16)
DEV void cp16(const unsigned short* g, unsigned short* l) {
  __builtin_amdgcn_global_load_lds(
      (const __attribute__((address_space(1))) void*)g,
      (__attribute__((address_space(3))) void*)l, 16, 0, 0);
}

// packed f32x2 -> bf16x2 (RNE), lo in low 16 bits
DEV unsigned int cvtpk(float lo, float hi) {
  unsigned int r;
  asm("v_cvt_pk_bf16_f32 %0, %1, %2" : "=v"(r) : "v"(lo), "v"(hi));
  return r;
}

// ---------------------------------------------------------------------------
// fp32 -> bf16 converts
// ---------------------------------------------------------------------------
__global__ void cvt_kernel(const float* __restrict__ in,
                           unsigned short* __restrict__ out, int n, float scale) {
  const int i = (blockIdx.x * blockDim.x + threadIdx.x) * 4;
  if (i < n) {
    const float4 v = *(const float4*)&in[i];
    short4v o;
    o[0] = (short)f2b(v.x * scale); o[1] = (short)f2b(v.y * scale);
    o[2] = (short)f2b(v.z * scale); o[3] = (short)f2b(v.w * scale);
    *(short4v*)&out[i] = o;
  }
}

// All 7 converts in one launch. Blocks [0,24576): x_Q/x_K/x_V (8192 each);
// [24576,28672): Wq/Wk/Wv/Wo (1024 each). Wq is pre-scaled by QSC.
__global__ void cvt_all(const float* __restrict__ xq, const float* __restrict__ xk,
                        const float* __restrict__ xv, const float* __restrict__ wq,
                        const float* __restrict__ wk, const float* __restrict__ wv,
                        const float* __restrict__ wo, unsigned short* __restrict__ X,
                        unsigned short* __restrict__ W) {
  const int b = blockIdx.x;
  const float* p;
  unsigned short* out;
  float scale = 1.f;
  int i;
  if (b < 24576) {
    const int seg = b >> 13, ib = b & 8191;
    p = (seg == 0) ? xq : (seg == 1) ? xk : xv;
    out = X + (size_t)seg * 8388608;
    i = (ib * 256 + threadIdx.x) * 4;
  } else {
    const int bb = b - 24576;
    const int seg = bb >> 10, ib = bb & 1023;
    p = (seg == 0) ? wq : (seg == 1) ? wk : (seg == 2) ? wv : wo;
    out = W + (size_t)seg * 1048576;
    if (seg == 0) scale = QSC;
    i = (ib * 256 + threadIdx.x) * 4;
  }
  const float4 v = *(const float4*)&p[i];
  short4v o;
  o[0] = (short)f2b(v.x * scale); o[1] = (short)f2b(v.y * scale);
  o[2] = (short)f2b(v.z * scale); o[3] = (short)f2b(v.w * scale);
  *(short4v*)&out[i] = o;
}

// ---------------------------------------------------------------------------
// NT GEMM body: Out = A[M,K] * W[N,K]^T + bias*bsc, bf16 in, fp32 accum.
// MODE 0: fp32 Out[m*N+n];  MODE 1: bf16 heads [bh][s][dk];  MODE 2: bf16 [bh][dk][s]
// 128x128 tile, BK=64, 4 waves, 4x4 MFMA/wave. LDS XOR-swizzled at 16B chunks.
// ---------------------------------------------------------------------------
template <int MODE>
DEV void gemm_tile_body(const unsigned short* __restrict__ A,
                        const unsigned short* __restrict__ W,
                        const float* __restrict__ bias, void* __restrict__ OutV,
                        unsigned short* sA, unsigned short* sB,
                        int M, int N, int K, float bsc) {
  const int tid = threadIdx.x;
  const int lane = tid & 63, wave = tid >> 6;
  const int lr = lane & 15, quad = lane >> 4;
  const int bm = blockIdx.x * 128, bn = blockIdx.y * 128;
  const int wm = (wave >> 1) * 64, wn = (wave & 1) * 64;
  const int srow = tid >> 3;                       // 0..31
  const int sdst = (tid & 7) * 8;                  // LDS chunk (forced layout)
  const int ssrc = ((tid & 7) ^ (srow & 7)) * 8;   // swizzled source chunk

  f32x4 acc[4][4] = {};

  for (int kt = 0; kt < K; kt += 64) {
#pragma unroll
    for (int is = 0; is < 4; ++is) {
      const int r = is * 32 + srow;
      cp16(&A[(size_t)(bm + r) * K + kt + ssrc], &sA[r * 64 + sdst]);
      cp16(&W[(size_t)(bn + r) * K + kt + ssrc], &sB[r * 64 + sdst]);
    }
    __syncthreads();
#pragma unroll
    for (int ks = 0; ks < 2; ++ks) {
      bf16x8 af[4], bf[4];
      const int co = (((ks * 4 + quad) ^ (lr & 7)) << 3);
#pragma unroll
      for (int i = 0; i < 4; ++i)
        af[i] = *(const bf16x8*)&sA[(wm + i * 16 + lr) * 64 + co];
#pragma unroll
      for (int j = 0; j < 4; ++j)
        bf[j] = *(const bf16x8*)&sB[(wn + j * 16 + lr) * 64 + co];
#pragma unroll
      for (int i = 0; i < 4; ++i)
#pragma unroll
        for (int j = 0; j < 4; ++j)
          acc[i][j] = __builtin_amdgcn_mfma_f32_16x16x32_bf16(af[i], bf[j], acc[i][j], 0, 0, 0);
    }
    __syncthreads();
  }

  // epilogue: C/D layout col = lane&15, row = quad*4 + reg
#pragma unroll
  for (int j = 0; j < 4; ++j) {
    const int n = bn + wn + j * 16 + lr;
    const float bv = bias[n] * bsc;
#pragma unroll
    for (int i = 0; i < 4; ++i) {
      const int mb = bm + wm + i * 16 + quad * 4;
#pragma unroll
      for (int r = 0; r < 4; ++r) {
        const int m = mb + r;
        const float o = acc[i][j][r] + bv;
        if (MODE == 0) {
          ((float*)OutV)[(size_t)m * N + n] = o;
        } else if (MODE == 1) {
          ((unsigned short*)OutV)[((size_t)((m >> 11) * 16 + (n >> 6)) * 2048 + (m & 2047)) * 64 + (n & 63)] = f2b(o);
        } else {
          ((unsigned short*)OutV)[((size_t)((m >> 11) * 16 + (n >> 6)) * 64 + (n & 63)) * 2048 + (m & 2047)] = f2b(o);
        }
      }
    }
  }
}

template <int MODE>
__global__ __launch_bounds__(256, 3) void gemm_bt(
    const unsigned short* __restrict__ A, const unsigned short* __restrict__ W,
    const float* __restrict__ bias, void* __restrict__ OutV,
    int M, int N, int K, float bsc) {
  __shared__ __align__(16) unsigned short sA[128 * 64];
  __shared__ __align__(16) unsigned short sB[128 * 64];
  gemm_tile_body<MODE>(A, W, bias, OutV, sA, sB, M, N, K, bsc);
}

// Batched Q/K/V projection: z=0 -> Q (MODE1, bias*QSC), z=1 -> K (MODE1), z=2 -> V (MODE2).
__global__ __launch_bounds__(256, 3) void gemm_qkv3(
    const unsigned short* __restrict__ Aall, const unsigned short* __restrict__ Wall,
    const float* __restrict__ b0, const float* __restrict__ b1,
    const float* __restrict__ b2, unsigned short* __restrict__ Out) {
  __shared__ __align__(16) unsigned short sA[128 * 64];
  __shared__ __align__(16) unsigned short sB[128 * 64];
  const int z = blockIdx.z;
  const unsigned short* A = Aall + (size_t)z * 8388608;
  const unsigned short* W = Wall + (size_t)z * 1048576;
  const float* bias = (z == 0) ? b0 : (z == 1) ? b1 : b2;
  const float bsc = (z == 0) ? QSC : 1.f;
  void* OutV = (void*)(Out + (size_t)z * 8388608);
  if (z == 2)
    gemm_tile_body<2>(A, W, bias, OutV, sA, sB, 8192, 1024, 1024, bsc);
  else
    gemm_tile_body<1>(A, W, bias, OutV, sA, sB, 8192, 1024, 1024, bsc);
}

// ---------------------------------------------------------------------------
// Flash attention. Q pre-scaled by 1/8*log2(e) at projection -> P = exp2(S).
// Tile split into two kv-halves [QKa->packa->PVa][QKb->packb->PVb]; only one
// 16-reg S accumulator and one pa[2] P-fragment set live at a time.
// 3 blocks/CU (launch_bounds(256,3)): 4/CU spills (round-2 regression:
// 128-reg unified budget < ~150 needed -> 150 MB scratch traffic).
// XCD-aware remap: each XCD owns 8 whole bh's -> K/V L2-resident.
// ---------------------------------------------------------------------------
#define ATTN_PACK8(SREG, RB, KD)                                               \
  {                                                                            \
    float pr[8];                                                               \
    _Pragma("unroll") for (int r = 0; r < 8; ++r) {                            \
      pr[r] = __builtin_amdgcn_exp2f(SREG[(RB) + r]);                          \
      rsp[r & 3] += pr[r];                                                     \
    }                                                                          \
    const u32x2 w02 = __builtin_amdgcn_permlane32_swap(                        \
        cvtpk(pr[0], pr[1]), cvtpk(pr[4], pr[5]), false, false);               \
    const u32x2 w13 = __builtin_amdgcn_permlane32_swap(                        \
        cvtpk(pr[2], pr[3]), cvtpk(pr[6], pr[7]), false, false);               \
    pa[KD].w[0] = w02[0]; pa[KD].w[1] = w13[0];                                \
    pa[KD].w[2] = w02[1]; pa[KD].w[3] = w13[1];                                \
  }

#define ATTN_TILE(T, SKB, SVB, DKB, DVB)                                       \
  {                                                                            \
    if ((T) + 1 < 32) {                                                        \
      const int kvn = ((T) + 1) * 64;                                          \
      _Pragma("unroll") for (int is = 0; is < 2; ++is) {                       \
        const int r = is * 32 + sr_;                                           \
        const int sw = (sc_ ^ ((r ^ (r >> 3)) & 7)) * 8;                       \
        cp16(&Kp[(size_t)(kvn + r) * 64 + sw], &DKB[r * 64 + sc_ * 8]);        \
        cp16(&Vp[(size_t)r * 2048 + kvn + sw], &DVB[r * 64 + sc_ * 8]);        \
      }                                                                        \
    }                                                                          \
    {                                                                          \
      f32x16 s0 = {};                                                          \
      __builtin_amdgcn_s_setprio(1);                                           \
      _Pragma("unroll") for (int ks = 0; ks < 4; ++ks) {                       \
        const bf16x8 k0 = *(const bf16x8*)&SKB[rowa + (((ks * 2 + b5) ^ swa) << 3)]; \
        s0 = __builtin_amdgcn_mfma_f32_32x32x16_bf16(k0, qf[ks], s0, 0, 0, 0); \
      }                                                                        \
      __builtin_amdgcn_s_setprio(0);                                           \
      ATTN_PACK8(s0, 0, 0)                                                     \
      ATTN_PACK8(s0, 8, 1)                                                     \
    }                                                                          \
    __builtin_amdgcn_s_setprio(1);                                             \
    _Pragma("unroll") for (int ks = 0; ks < 2; ++ks) {                         \
      const bf16x8 va = *(const bf16x8*)&SVB[rowa + (((ks * 2 + b5) ^ swa) << 3)]; \
      const bf16x8 vb = *(const bf16x8*)&SVB[rowb + (((ks * 2 + b5) ^ swb) << 3)]; \
      oacc0 = __builtin_amdgcn_mfma_f32_32x32x16_bf16(pa[ks].v, va, oacc0, 0, 0, 0); \
      oacc1 = __builtin_amdgcn_mfma_f32_32x32x16_bf16(pa[ks].v, vb, oacc1, 0, 0, 0); \
    }                                                                          \
    __builtin_amdgcn_s_setprio(0);                                             \
    {                                                                          \
      f32x16 s1 = {};                                                          \
      __builtin_amdgcn_s_setprio(1);                                           \
      _Pragma("unroll") for (int ks = 0; ks < 4; ++ks) {                       \
        const bf16x8 k1 = *(const bf16x8*)&SKB[rowb + (((ks * 2 + b5) ^ swb) << 3)]; \
        s1 = __builtin_amdgcn_mfma_f32_32x32x16_bf16(k1, qf[ks], s1, 0, 0, 0); \
      }                                                                        \
      __builtin_amdgcn_s_setprio(0);                                           \
      ATTN_PACK8(s1, 0, 0)                                                     \
      ATTN_PACK8(s1, 8, 1)                                                     \
    }                                                                          \
    __builtin_amdgcn_s_setprio(1);                                             \
    _Pragma("unroll") for (int ks = 2; ks < 4; ++ks) {                         \
      const bf16x8 va = *(const bf16x8*)&SVB[rowa + (((ks * 2 + b5) ^ swa) << 3)]; \
      const bf16x8 vb = *(const bf16x8*)&SVB[rowb + (((ks * 2 + b5) ^ swb) << 3)]; \
      oacc0 = __builtin_amdgcn_mfma_f32_32x32x16_bf16(pa[ks - 2].v, va, oacc0, 0, 0, 0); \
      oacc1 = __builtin_amdgcn_mfma_f32_32x32x16_bf16(pa[ks - 2].v, vb, oacc1, 0, 0, 0); \
    }                                                                          \
    __builtin_amdgcn_s_setprio(0);                                             \
    __syncthreads();                                                           \
  }

__global__ __launch_bounds__(256, 3) void attn_kernel(
    const unsigned short* __restrict__ Qb, const unsigned short* __restrict__ Kb,
    const unsigned short* __restrict__ Vt, unsigned short* __restrict__ Ob) {
  __shared__ __align__(16) unsigned short sK[2][64 * 64];   // [buf][kv][dk]
  __shared__ __align__(16) unsigned short sV[2][64 * 64];   // [buf][dk][kv]

  const int tid = threadIdx.x;
  const int lane = tid & 63;
  const int wave = tid >> 6;
  const int c31 = lane & 31;
  const int b5 = lane >> 5;

  // XCD-aware remap: linear wg -> XCD = wg&7 (round-robin). Give XCD x the
  // 8 bh's [8x, 8x+8) so each bh's K/V (512 KB) stays in one XCD's L2.
  const int wg = blockIdx.y * 16 + blockIdx.x;
  const int j = wg >> 3;
  const int bh = (wg & 7) * 8 + (j >> 4);
  const int q0 = (j & 15) * 128 + wave * 32;

  const size_t base = (size_t)bh * (2048 * 64);
  const unsigned short* __restrict__ Qp = Qb + base;
  const unsigned short* __restrict__ Kp = Kb + base;
  const unsigned short* __restrict__ Vp = Vt + base;

  // Q fragments (pre-scaled): B-operand, lane holds Q[q=c31][dk = ks*16 + b5*8 + j]
  bf16x8 qf[4];
#pragma unroll
  for (int ks = 0; ks < 4; ++ks)
    qf[ks] = *(const bf16x8*)&Qp[(size_t)(q0 + c31) * 64 + ks * 16 + b5 * 8];

  f32x16 oacc0 = {}, oacc1 = {};   // O[q=crow(r,b5)][dk = {c31, 32+c31}]
  float rsp[4] = {0.f, 0.f, 0.f, 0.f};  // 4 independent denom chains
  union PA { unsigned int w[4]; bf16x8 v; };
  PA pa[2];

  const int sr_ = tid >> 3;        // stage row-in-32
  const int sc_ = tid & 7;         // stage dest chunk (forced linear layout)

  const int swa = (c31 ^ (c31 >> 3)) & 7;  // swizzle for row = c31
  const int swb = swa ^ 4;                 // swizzle for row = 32 + c31
  const int rowa = c31 * 64, rowb = (32 + c31) * 64;

  unsigned short* sK0 = &sK[0][0];
  unsigned short* sK1 = &sK[1][0];
  unsigned short* sV0 = &sV[0][0];
  unsigned short* sV1 = &sV[1][0];

  // prologue: stage tile 0
#pragma unroll
  for (int is = 0; is < 2; ++is) {
    const int r = is * 32 + sr_;
    const int sw = (sc_ ^ ((r ^ (r >> 3)) & 7)) * 8;
    cp16(&Kp[(size_t)r * 64 + sw], &sK0[r * 64 + sc_ * 8]);
    cp16(&Vp[(size_t)r * 2048 + sw], &sV0[r * 64 + sc_ * 8]);
  }
  __syncthreads();

  for (int t = 0; t < 32; t += 2) {
    ATTN_TILE(t, sK0, sV0, sK1, sV1);
    ATTN_TILE(t + 1, sK1, sV1, sK0, sV0);
  }

  // finish denominator (q = c31 split across b5 halves), scale, store
  float rs = (rsp[0] + rsp[1]) + (rsp[2] + rsp[3]);
  rs += __shfl_xor(rs, 32);
  const float linv = 1.f / rs;
  const int b = bh >> 4, h = bh & 15;
#pragma unroll
  for (int r = 0; r < 16; ++r) {
    const int crow = (r & 3) + 8 * (r >> 2) + 4 * b5;  // q-local of oacc row r
    const float li = __shfl(linv, crow);               // linv lives at lane q
    unsigned short* op = &Ob[(size_t)(b * 2048 + q0 + crow) * 1024 + h * 64];
    op[c31] = f2b(oacc0[r] * li);
    op[32 + c31] = f2b(oacc1[r] * li);
  }
}

extern "C" void kernel_launch(void* const* d_in, const int* in_sizes, int n_in,
                              void* d_out, int out_size, void* d_ws, size_t ws_size,
                              hipStream_t stream) {
  const float* xq = (const float*)d_in[0];
  const float* xk = (const float*)d_in[1];
  const float* xv = (const float*)d_in[2];
  const float* Wq = (const float*)d_in[3];
  const float* bq = (const float*)d_in[4];
  const float* Wk = (const float*)d_in[5];
  const float* bk = (const float*)d_in[6];
  const float* Wv = (const float*)d_in[7];
  const float* bv = (const float*)d_in[8];
  const float* Wo = (const float*)d_in[9];
  const float* bo = (const float*)d_in[10];

  unsigned short* ws = (unsigned short*)d_ws;
  const size_t SZ = (size_t)8192 * 1024;   // 8M bf16 elems
  const size_t WSZ = (size_t)1024 * 1024;  // 1M bf16 elems

  if (ws_size >= (6 * SZ + 4 * WSZ) * sizeof(unsigned short)) {
    // big-workspace path: 4 launches total
    unsigned short* Xall = ws;                 // 3 x 8M (xq,xk,xv); [0:8M) reused as attn out
    unsigned short* Wall = ws + 3 * SZ;        // 4 x 1M (Wq*QSC, Wk, Wv, Wo)
    unsigned short* Qb = Wall + 4 * WSZ;       // [bh][s][dk]
    unsigned short* Kb = Qb + SZ;              // [bh][s][dk]
    unsigned short* Vt = Kb + SZ;              // [bh][dk][s]

    hipLaunchKernelGGL(cvt_all, dim3(28672), dim3(256), 0, stream,
                       xq, xk, xv, Wq, Wk, Wv, Wo, Xall, Wall);
    hipLaunchKernelGGL(gemm_qkv3, dim3(64, 8, 3), dim3(256), 0, stream,
                       Xall, Wall, bq, bk, bv, Qb);
    hipLaunchKernelGGL(attn_kernel, dim3(16, 64), dim3(256), 0, stream, Qb, Kb, Vt, Xall);
    hipLaunchKernelGGL((gemm_bt<0>), dim3(64, 8), dim3(256), 0, stream,
                       Xall, Wall + 3 * WSZ, bo, d_out, 8192, 1024, 1024, 1.f);
  } else {
    // fallback: sequential buffer-reuse path
    unsigned short* X  = ws;                 // reused: cvt(x_*), then attn output
    unsigned short* Wb = ws + SZ;            // 1M, reused per weight
    unsigned short* Qb = ws + SZ + SZ / 8;   // [bh][s][dk]
    unsigned short* Kb = Qb + SZ;            // [bh][s][dk]
    unsigned short* Vt = Kb + SZ;            // [bh][dk][s]

    const int NX = 8192 * 1024, NW = 1024 * 1024;
    dim3 cbx(256), cgx(NX / 1024), cgw(NW / 1024);
    dim3 gg(64, 8), bb(256);

    hipLaunchKernelGGL(cvt_kernel, cgx, cbx, 0, stream, xq, X, NX, 1.f);
    hipLaunchKernelGGL(cvt_kernel, cgw, cbx, 0, stream, Wq, Wb, NW, QSC);
    hipLaunchKernelGGL((gemm_bt<1>), gg, bb, 0, stream, X, Wb, bq, (void*)Qb, 8192, 1024, 1024, QSC);

    hipLaunchKernelGGL(cvt_kernel, cgx, cbx, 0, stream, xk, X, NX, 1.f);
    hipLaunchKernelGGL(cvt_kernel, cgw, cbx, 0, stream, Wk, Wb, NW, 1.f);
    hipLaunchKernelGGL((gemm_bt<1>), gg, bb, 0, stream, X, Wb, bk, (void*)Kb, 8192, 1024, 1024, 1.f);

    hipLaunchKernelGGL(cvt_kernel, cgx, cbx, 0, stream, xv, X, NX, 1.f);
    hipLaunchKernelGGL(cvt_kernel, cgw, cbx, 0, stream, Wv, Wb, NW, 1.f);
    hipLaunchKernelGGL((gemm_bt<2>), gg, bb, 0, stream, X, Wb, bv, (void*)Vt, 8192, 1024, 1024, 1.f);

    hipLaunchKernelGGL(attn_kernel, dim3(16, 64), bb, 0, stream, Qb, Kb, Vt, X);

    hipLaunchKernelGGL(cvt_kernel, cgw, cbx, 0, stream, Wo, Wb, NW, 1.f);
    hipLaunchKernelGGL((gemm_bt<0>), gg, bb, 0, stream, X, Wb, bo, d_out, 8192, 1024, 1024, 1.f);
  }
}